// Round 7
// baseline (348.243 us; speedup 1.0000x reference)
//
#include <hip/hip_runtime.h>

#define N_NODES 65536
#define IN_FEAT 16
#define HIDDEN 32
#define NUM_EDGES 1048576
#define NUM_GRAPHS 16
#define NODES_PER_GRAPH 4096
#define FC1_IN (NODES_PER_GRAPH * HIDDEN) /* 131072 */
#define FC1_OUT 256
#define FC2_OUT 64
#define FC1_KCHUNK 128
#define FC1_BLOCKS (FC1_IN / FC1_KCHUNK) /* 1024 */
#define NB 256          /* buckets = dst>>8 */
#define BUCKET_CAP 5120 /* mean 4096, sd 64 -> 16 sigma headroom */
#define EPB_A 4096      /* edges per phase-A block */

typedef _Float16 half8 __attribute__((ext_vector_type(8)));  // 16 B
typedef _Float16 half4v __attribute__((ext_vector_type(4))); // 8 B

// ---- init bucket cursors to fixed-capacity bases ----
__global__ void initcur_kernel(int* __restrict__ bucket_cursor) {
    bucket_cursor[threadIdx.x] = threadIdx.x * BUCKET_CAP;
}

// ---- phase A: bin edges by dst>>8 with chunk-contiguous writes ----
__global__ void binA_kernel(const int* __restrict__ src, const int* __restrict__ dst,
                            int* __restrict__ bucket_cursor, int* __restrict__ binned) {
    __shared__ int hist[NB];
    __shared__ int base[NB];
    __shared__ int cur[NB];
    int t = threadIdx.x;
    hist[t] = 0;
    __syncthreads();
    int e0 = blockIdx.x * EPB_A;
    int s[16], d[16];
#pragma unroll
    for (int i = 0; i < 16; i++) {
        int e = e0 + t + 256 * i;
        s[i] = src[e];
        d[i] = dst[e];
    }
#pragma unroll
    for (int i = 0; i < 16; i++) atomicAdd(&hist[d[i] >> 8], 1);
    __syncthreads();
    base[t] = atomicAdd(&bucket_cursor[t], hist[t]);
    cur[t] = 0;
    __syncthreads();
#pragma unroll
    for (int i = 0; i < 16; i++) {
        int b = d[i] >> 8;
        int r = atomicAdd(&cur[b], 1);
        binned[base[b] + r] = s[i] | ((d[i] & 255) << 16);
    }
}

// ---- phase B: per-bucket LDS counting sort by dst low byte ----
// emits csr (ushort), rowstart/rowend, dinv, and p0 = x*dinv in fp16.
__global__ void sortB_kernel(const int* __restrict__ bucket_cursor, const int* __restrict__ binned,
                             unsigned short* __restrict__ csr, int* __restrict__ rowstart,
                             int* __restrict__ rowend, float* __restrict__ dinv,
                             const float* __restrict__ x, half8* __restrict__ p0) {
    __shared__ int hist[NB];
    __shared__ int scanbuf[NB];
    __shared__ int start[NB];
    __shared__ int cur[NB];
    int t = threadIdx.x;
    int b = blockIdx.x;
    int bbase = b * BUCKET_CAP;
    int cnt = bucket_cursor[b] - bbase;
    hist[t] = 0;
    __syncthreads();
    for (int i = t; i < cnt; i += 256) atomicAdd(&hist[binned[bbase + i] >> 16], 1);
    __syncthreads();
    int v = hist[t];
    scanbuf[t] = v;
    __syncthreads();
    for (int off = 1; off < 256; off <<= 1) {
        int y = (t >= off) ? scanbuf[t - off] : 0;
        __syncthreads();
        scanbuf[t] += y;
        __syncthreads();
    }
    int excl = scanbuf[t] - v;  // exclusive prefix within bucket
    start[t] = excl;
    cur[t] = 0;
    __syncthreads();
    for (int i = t; i < cnt; i += 256) {
        int p = binned[bbase + i];
        int dl = p >> 16;
        int r = atomicAdd(&cur[dl], 1);
        csr[bbase + start[dl] + r] = (unsigned short)(p & 0xFFFF);
    }
    int n = b * 256 + t;
    rowstart[n] = bbase + excl;
    rowend[n] = bbase + excl + v;
    float di = rsqrtf((float)v + 1.0f);
    dinv[n] = di;
    const float4* x4 = (const float4*)x;
#pragma unroll
    for (int q = 0; q < 2; q++) {
        float4 a = x4[(size_t)n * 4 + 2 * q];
        float4 c = x4[(size_t)n * 4 + 2 * q + 1];
        half8 hh;
        hh[0] = (_Float16)(a.x * di); hh[1] = (_Float16)(a.y * di);
        hh[2] = (_Float16)(a.z * di); hh[3] = (_Float16)(a.w * di);
        hh[4] = (_Float16)(c.x * di); hh[5] = (_Float16)(c.y * di);
        hh[6] = (_Float16)(c.z * di); hh[7] = (_Float16)(c.w * di);
        p0[(size_t)n * 2 + q] = hh;
    }
}

// ---- fused conv: gather (fp16 p rows, fp32 accum) -> LDS q tile -> matmul ----
// q[n] = sum_{s in N(n)} p[s] + p[n];  v = relu(dinv[n]*(q[n]@W) + b)
// LAST: store fp32 h3; else store p_next = v*dinv in fp16.
// FIN in-feats, F8 = FIN/8 half8-chunks per row, NPB = 256/F8 nodes per block.
template <int FIN, int F8, int LOG2F8, bool LAST>
__global__ void conv_kernel(const int* __restrict__ rowstart, const int* __restrict__ rowend,
                            const unsigned short* __restrict__ csr, const half8* __restrict__ p,
                            const float* __restrict__ W, const float* __restrict__ bias,
                            const float* __restrict__ dinv, void* __restrict__ outp) {
    constexpr int NPB = 256 / F8;
    __shared__ float4 Ws4[FIN * 8];        // W[FIN][32] as float4
    __shared__ float qs[NPB][FIN + 1];     // +1 pad
    int t = threadIdx.x;
    for (int i = t; i < FIN * 8; i += 256) Ws4[i] = ((const float4*)W)[i];

    // ---- gather stage: this thread owns (node nl, half8-chunk f8) ----
    int f8 = t & (F8 - 1);
    int nl = t >> LOG2F8;
    int n = blockIdx.x * NPB + nl;
    half8 self = p[(size_t)n * F8 + f8];
    float acc[8];
#pragma unroll
    for (int e = 0; e < 8; e++) acc[e] = (float)self[e];
    int beg = rowstart[n];
    int end = rowend[n];
    int i = beg;
    for (; i + 8 <= end; i += 8) {
        int s[8];
#pragma unroll
        for (int u = 0; u < 8; u++) s[u] = csr[i + u];
        half8 a[8];
#pragma unroll
        for (int u = 0; u < 8; u++) a[u] = p[(size_t)s[u] * F8 + f8];
#pragma unroll
        for (int u = 0; u < 8; u++)
#pragma unroll
            for (int e = 0; e < 8; e++) acc[e] += (float)a[u][e];
    }
    if (i + 4 <= end) {
        int s[4];
#pragma unroll
        for (int u = 0; u < 4; u++) s[u] = csr[i + u];
        half8 a[4];
#pragma unroll
        for (int u = 0; u < 4; u++) a[u] = p[(size_t)s[u] * F8 + f8];
#pragma unroll
        for (int u = 0; u < 4; u++)
#pragma unroll
            for (int e = 0; e < 8; e++) acc[e] += (float)a[u][e];
        i += 4;
    }
    for (; i < end; i++) {
        half8 a = p[(size_t)csr[i] * F8 + f8];
#pragma unroll
        for (int e = 0; e < 8; e++) acc[e] += (float)a[e];
    }
#pragma unroll
    for (int e = 0; e < 8; e++) qs[nl][f8 * 8 + e] = acc[e];
    __syncthreads();

    // ---- matmul stage: NPB nodes x 8 float4-outputs, NPB/32 per thread ----
    int fo4 = t & 7;
    int nb = t >> 3;  // 0..31
    float4 bb = ((const float4*)bias)[fo4];
#pragma unroll
    for (int k = 0; k < NPB / 32; k++) {
        int nn = nb + 32 * k;
        float4 a = make_float4(0.f, 0.f, 0.f, 0.f);
#pragma unroll
        for (int fi = 0; fi < FIN; fi++) {
            float r = qs[nn][fi];
            float4 wv = Ws4[fi * 8 + fo4];
            a.x += r * wv.x;
            a.y += r * wv.y;
            a.z += r * wv.z;
            a.w += r * wv.w;
        }
        int gn = blockIdx.x * NPB + nn;
        float di = dinv[gn];
        float4 v;
        v.x = a.x * di + bb.x;
        v.y = a.y * di + bb.y;
        v.z = a.z * di + bb.z;
        v.w = a.w * di + bb.w;
        v.x = v.x > 0.f ? v.x : 0.f;
        v.y = v.y > 0.f ? v.y : 0.f;
        v.z = v.z > 0.f ? v.z : 0.f;
        v.w = v.w > 0.f ? v.w : 0.f;
        if (LAST) {
            ((float4*)outp)[(size_t)gn * 8 + fo4] = v;
        } else {
            half4v hv;
            hv[0] = (_Float16)(v.x * di);
            hv[1] = (_Float16)(v.y * di);
            hv[2] = (_Float16)(v.z * di);
            hv[3] = (_Float16)(v.w * di);
            ((half4v*)outp)[(size_t)gn * 8 + fo4] = hv;
        }
    }
}

// ---- fc1 partials: part[b][g][j] = sum_{k in chunk b} h3[g][k]*w[k][j] ----
// 8-deep load pipeline: 8 independent float4 weight loads in flight/thread.
__global__ void fc1_kernel(const float* __restrict__ h3, const float* __restrict__ w,
                           float* __restrict__ part) {
    __shared__ float hs[NUM_GRAPHS * FC1_KCHUNK];  // 8 KB
    int t = threadIdx.x;
    int kbase = blockIdx.x * FC1_KCHUNK;
    for (int i = t; i < NUM_GRAPHS * FC1_KCHUNK; i += 256) {
        int g = i >> 7;  // FC1_KCHUNK == 128
        int kk = i & 127;
        hs[i] = h3[(size_t)g * FC1_IN + kbase + kk];
    }
    __syncthreads();
    int kl = t & 3;
    int c = t >> 2;
    float4 acc[NUM_GRAPHS];
#pragma unroll
    for (int g = 0; g < NUM_GRAPHS; g++) acc[g] = make_float4(0.f, 0.f, 0.f, 0.f);
    const float4* w4 = (const float4*)w;  // row k = 64 float4
    for (int i0 = 0; i0 < FC1_KCHUNK / 4; i0 += 8) {
        float4 wv[8];
#pragma unroll
        for (int u = 0; u < 8; u++)  // 8 independent 16B loads in flight
            wv[u] = w4[(size_t)(kbase + kl + 4 * (i0 + u)) * (FC1_OUT / 4) + c];
#pragma unroll
        for (int u = 0; u < 8; u++) {
            int kk = kl + 4 * (i0 + u);
#pragma unroll
            for (int g = 0; g < NUM_GRAPHS; g++) {
                float hg = hs[g * FC1_KCHUNK + kk];
                acc[g].x += hg * wv[u].x;
                acc[g].y += hg * wv[u].y;
                acc[g].z += hg * wv[u].z;
                acc[g].w += hg * wv[u].w;
            }
        }
    }
#pragma unroll
    for (int g = 0; g < NUM_GRAPHS; g++) {
        acc[g].x += __shfl_xor(acc[g].x, 1);
        acc[g].y += __shfl_xor(acc[g].y, 1);
        acc[g].z += __shfl_xor(acc[g].z, 1);
        acc[g].w += __shfl_xor(acc[g].w, 1);
        acc[g].x += __shfl_xor(acc[g].x, 2);
        acc[g].y += __shfl_xor(acc[g].y, 2);
        acc[g].z += __shfl_xor(acc[g].z, 2);
        acc[g].w += __shfl_xor(acc[g].w, 2);
    }
    if (kl == 0) {
        float4* p4 = (float4*)part;
#pragma unroll
        for (int g = 0; g < NUM_GRAPHS; g++)
            p4[(size_t)blockIdx.x * (NUM_GRAPHS * FC1_OUT / 4) + g * (FC1_OUT / 4) + c] = acc[g];
    }
}

// ---- reduce partials: out1[j'] += sum over 1024 blocks ----
__global__ void reduce_kernel(const float* __restrict__ part, float* __restrict__ out1) {
    int tid = blockIdx.x * 256 + threadIdx.x;  // 32768 threads
    int j = tid & 4095;
    int bq = tid >> 12;  // 0..7
    float s = 0.f;
#pragma unroll 8
    for (int u = 0; u < FC1_BLOCKS / 8; u++)
        s += part[(size_t)(bq * (FC1_BLOCKS / 8) + u) * (NUM_GRAPHS * FC1_OUT) + j];
    atomicAdd(&out1[j], s);
}

// ---- fc2 ----
__global__ void fc2_kernel(const float* __restrict__ out1, const float* __restrict__ fc1_b,
                           const float* __restrict__ w2, const float* __restrict__ b2,
                           float* __restrict__ out) {
    int g = blockIdx.x;
    int j = threadIdx.x;  // 0..63
    __shared__ float vs[FC1_OUT];
    for (int k = threadIdx.x; k < FC1_OUT; k += 64) {
        float v = out1[g * FC1_OUT + k] + fc1_b[k];
        vs[k] = v > 0.f ? v : 0.f;
    }
    __syncthreads();
    float acc = b2[j];
    for (int k = 0; k < FC1_OUT; k++) acc += vs[k] * w2[k * FC2_OUT + j];
    out[g * FC2_OUT + j] = acc;
}

extern "C" void kernel_launch(void* const* d_in, const int* in_sizes, int n_in,
                              void* d_out, int out_size, void* d_ws, size_t ws_size,
                              hipStream_t stream) {
    const float* x = (const float*)d_in[0];
    const int* ei = (const int*)d_in[1];
    const int* src = ei;
    const int* dst = ei + NUM_EDGES;
    const float* W1 = (const float*)d_in[2];
    const float* b1 = (const float*)d_in[3];
    const float* W2 = (const float*)d_in[4];
    const float* b2 = (const float*)d_in[5];
    const float* W3 = (const float*)d_in[6];
    const float* b3 = (const float*)d_in[7];
    const float* fc1_w = (const float*)d_in[8];
    const float* fc1_b = (const float*)d_in[9];
    const float* fc2_w = (const float*)d_in[10];
    const float* fc2_b = (const float*)d_in[11];
    float* out = (float*)d_out;

    // workspace layout (re-poisoned 0xAA each call; zero what we RMW)
    int* bucket_cursor = (int*)d_ws;                       // 1 KB
    int* binned = bucket_cursor + 256;                     // 5.24 MB
    unsigned short* csr = (unsigned short*)(binned + NB * BUCKET_CAP);  // 2.62 MB
    int* rowstart = (int*)(csr + NB * BUCKET_CAP);         // 256 KB
    int* rowend = rowstart + N_NODES;                      // 256 KB
    float* dinv = (float*)(rowend + N_NODES);              // 256 KB
    half8* p0 = (half8*)(dinv + N_NODES);                  // N*16 fp16 = 2 MB
    half8* pA = (half8*)(p0 + (size_t)N_NODES * 2);        // N*32 fp16 = 4 MB
    half8* pB = (half8*)(pA + (size_t)N_NODES * 4);        // N*32 fp16 = 4 MB
    float* h3 = (float*)(pB + (size_t)N_NODES * 4);        // N*32 f32 = 8 MB
    float* out1 = h3 + (size_t)N_NODES * HIDDEN;           // 16 KB
    float* part = out1 + NUM_GRAPHS * FC1_OUT;             // 16 MB

    initcur_kernel<<<1, 256, 0, stream>>>(bucket_cursor);
    binA_kernel<<<NUM_EDGES / EPB_A, 256, 0, stream>>>(src, dst, bucket_cursor, binned);
    sortB_kernel<<<NB, 256, 0, stream>>>(bucket_cursor, binned, csr, rowstart, rowend, dinv, x, p0);

    // layer 1: 16-feat gather + matmul W1 -> pA (fp16)
    conv_kernel<IN_FEAT, 2, 1, false><<<N_NODES / 128, 256, 0, stream>>>(
        rowstart, rowend, csr, p0, W1, b1, dinv, pA);
    // layer 2: 32-feat gather + matmul W2 -> pB (fp16)
    conv_kernel<HIDDEN, 4, 2, false><<<N_NODES / 64, 256, 0, stream>>>(
        rowstart, rowend, csr, pA, W2, b2, dinv, pB);
    // layer 3: 32-feat gather + matmul W3 -> h3 (fp32)
    conv_kernel<HIDDEN, 4, 2, true><<<N_NODES / 64, 256, 0, stream>>>(
        rowstart, rowend, csr, pB, W3, b3, dinv, h3);

    fc1_kernel<<<FC1_BLOCKS, 256, 0, stream>>>(h3, fc1_w, part);
    hipMemsetAsync(out1, 0, NUM_GRAPHS * FC1_OUT * sizeof(float), stream);
    reduce_kernel<<<128, 256, 0, stream>>>(part, out1);
    fc2_kernel<<<NUM_GRAPHS, 64, 0, stream>>>(out1, fc1_b, fc2_w, fc2_b, out);
}

// Round 8
// 327.117 us; speedup vs baseline: 1.0646x; 1.0646x over previous
//
#include <hip/hip_runtime.h>

#define N_NODES 65536
#define IN_FEAT 16
#define HIDDEN 32
#define NUM_EDGES 1048576
#define NUM_GRAPHS 16
#define NODES_PER_GRAPH 4096
#define FC1_IN (NODES_PER_GRAPH * HIDDEN) /* 131072 */
#define FC1_OUT 256
#define FC2_OUT 64
#define FC1_KCHUNK 128
#define FC1_BLOCKS (FC1_IN / FC1_KCHUNK) /* 1024 */
#define NB 256          /* buckets = dst>>8 */
#define BUCKET_CAP 5120 /* mean 4096, sd 64 -> 16 sigma headroom */
#define EPB_A 4096      /* edges per phase-A block */

typedef _Float16 half8 __attribute__((ext_vector_type(8)));  // 16 B
typedef _Float16 half4v __attribute__((ext_vector_type(4))); // 8 B

// ---- init bucket cursors to fixed-capacity bases ----
__global__ void initcur_kernel(int* __restrict__ bucket_cursor) {
    bucket_cursor[threadIdx.x] = threadIdx.x * BUCKET_CAP;
}

// ---- phase A: bin edges by dst>>8 with chunk-contiguous writes ----
__global__ void binA_kernel(const int* __restrict__ src, const int* __restrict__ dst,
                            int* __restrict__ bucket_cursor, int* __restrict__ binned) {
    __shared__ int hist[NB];
    __shared__ int base[NB];
    __shared__ int cur[NB];
    int t = threadIdx.x;
    hist[t] = 0;
    __syncthreads();
    int e0 = blockIdx.x * EPB_A;
    int s[16], d[16];
#pragma unroll
    for (int i = 0; i < 16; i++) {
        int e = e0 + t + 256 * i;
        s[i] = src[e];
        d[i] = dst[e];
    }
#pragma unroll
    for (int i = 0; i < 16; i++) atomicAdd(&hist[d[i] >> 8], 1);
    __syncthreads();
    base[t] = atomicAdd(&bucket_cursor[t], hist[t]);
    cur[t] = 0;
    __syncthreads();
#pragma unroll
    for (int i = 0; i < 16; i++) {
        int b = d[i] >> 8;
        int r = atomicAdd(&cur[b], 1);
        binned[base[b] + r] = s[i] | ((d[i] & 255) << 16);
    }
}

// ---- phase B: per-bucket LDS counting sort by dst low byte (512 threads) ----
// emits csr (ushort), rowstart/rowend, dinv, and p0 = x*dinv in fp16.
__global__ void sortB_kernel(const int* __restrict__ bucket_cursor, const int* __restrict__ binned,
                             unsigned short* __restrict__ csr, int* __restrict__ rowstart,
                             int* __restrict__ rowend, float* __restrict__ dinv,
                             const float* __restrict__ x, half8* __restrict__ p0) {
    __shared__ int hist[NB];
    __shared__ int scanbuf[NB];
    __shared__ int start[NB];
    __shared__ int cur[NB];
    int t = threadIdx.x;  // 0..511
    int b = blockIdx.x;
    int bbase = b * BUCKET_CAP;
    int cnt = bucket_cursor[b] - bbase;
    if (t < NB) hist[t] = 0;
    __syncthreads();
    for (int i = t; i < cnt; i += 512) atomicAdd(&hist[binned[bbase + i] >> 16], 1);
    __syncthreads();
    int v = 0;
    if (t < NB) {
        v = hist[t];
        scanbuf[t] = v;
    }
    __syncthreads();
    for (int off = 1; off < NB; off <<= 1) {
        int y = 0;
        if (t < NB && t >= off) y = scanbuf[t - off];
        __syncthreads();
        if (t < NB) scanbuf[t] += y;
        __syncthreads();
    }
    if (t < NB) {
        start[t] = scanbuf[t] - v;  // exclusive prefix within bucket
        cur[t] = 0;
    }
    __syncthreads();
    for (int i = t; i < cnt; i += 512) {
        int p = binned[bbase + i];
        int dl = p >> 16;
        int r = atomicAdd(&cur[dl], 1);
        csr[bbase + start[dl] + r] = (unsigned short)(p & 0xFFFF);
    }
    if (t < NB) {
        int n = b * NB + t;
        int excl = start[t];
        rowstart[n] = bbase + excl;
        rowend[n] = bbase + excl + v;
        dinv[n] = rsqrtf((float)v + 1.0f);
    }
    // p0 prescale: 512 threads = 256 nodes x 2 half8-chunks
    {
        int nl = t >> 1;
        int qq = t & 1;
        int n = b * NB + nl;
        float di = rsqrtf((float)hist[nl] + 1.0f);
        const float4* x4 = (const float4*)x;
        float4 a = x4[(size_t)n * 4 + 2 * qq];
        float4 c = x4[(size_t)n * 4 + 2 * qq + 1];
        half8 hh;
        hh[0] = (_Float16)(a.x * di); hh[1] = (_Float16)(a.y * di);
        hh[2] = (_Float16)(a.z * di); hh[3] = (_Float16)(a.w * di);
        hh[4] = (_Float16)(c.x * di); hh[5] = (_Float16)(c.y * di);
        hh[6] = (_Float16)(c.z * di); hh[7] = (_Float16)(c.w * di);
        p0[(size_t)n * 2 + qq] = hh;
    }
}

// ---- gather: q[n] = sum_{s in N(n)} p[s] + p[n]; pure fp32 sum of fp16 rows ----
template <int F8, int LOG2F8>
__global__ void gather_kernel(const int* __restrict__ rowstart, const int* __restrict__ rowend,
                              const unsigned short* __restrict__ csr,
                              const half8* __restrict__ p, float* __restrict__ q) {
    int t = blockIdx.x * 256 + threadIdx.x;
    int f8 = t & (F8 - 1);
    int n = t >> LOG2F8;
    half8 self = p[(size_t)n * F8 + f8];
    float acc[8];
#pragma unroll
    for (int e = 0; e < 8; e++) acc[e] = (float)self[e];
    int beg = rowstart[n];
    int end = rowend[n];
    int i = beg;
    for (; i + 8 <= end; i += 8) {
        int s[8];
#pragma unroll
        for (int u = 0; u < 8; u++) s[u] = csr[i + u];
        half8 a[8];
#pragma unroll
        for (int u = 0; u < 8; u++) a[u] = p[(size_t)s[u] * F8 + f8];
#pragma unroll
        for (int u = 0; u < 8; u++)
#pragma unroll
            for (int e = 0; e < 8; e++) acc[e] += (float)a[u][e];
    }
    if (i + 4 <= end) {
        int s[4];
#pragma unroll
        for (int u = 0; u < 4; u++) s[u] = csr[i + u];
        half8 a[4];
#pragma unroll
        for (int u = 0; u < 4; u++) a[u] = p[(size_t)s[u] * F8 + f8];
#pragma unroll
        for (int u = 0; u < 4; u++)
#pragma unroll
            for (int e = 0; e < 8; e++) acc[e] += (float)a[u][e];
        i += 4;
    }
    for (; i < end; i++) {
        half8 a = p[(size_t)csr[i] * F8 + f8];
#pragma unroll
        for (int e = 0; e < 8; e++) acc[e] += (float)a[e];
    }
    float4 lo = make_float4(acc[0], acc[1], acc[2], acc[3]);
    float4 hi = make_float4(acc[4], acc[5], acc[6], acc[7]);
    float4* q4 = (float4*)q;
    q4[((size_t)n * F8 + f8) * 2] = lo;
    q4[((size_t)n * F8 + f8) * 2 + 1] = hi;
}

// ---- matmul: v = relu(dinv[n]*(q[n]@W) + b); LAST: store fp32 h3, else p=v*dinv fp16 ----
template <int FIN, bool LAST>
__global__ void matmul_kernel(const float* __restrict__ q, const float* __restrict__ W,
                              const float* __restrict__ bias, const float* __restrict__ dinv,
                              void* __restrict__ outp) {
    __shared__ float4 Ws4[FIN * 8];           // W[FIN][32] as float4
    __shared__ float rows[32 * (FIN + 1)];    // +1 pad: conflict-free nl stride
    int t = threadIdx.x;
    for (int i = t; i < FIN * 8; i += 256) Ws4[i] = ((const float4*)W)[i];
    size_t base = (size_t)blockIdx.x * 32 * FIN;
    for (int i = t; i < 32 * FIN; i += 256) {
        int nn = i / FIN;
        int ff = i & (FIN - 1);
        rows[nn * (FIN + 1) + ff] = q[base + i];
    }
    __syncthreads();
    int fo4 = t & 7;
    int nl = t >> 3;
    int n = blockIdx.x * 32 + nl;
    float4 acc = make_float4(0.f, 0.f, 0.f, 0.f);
#pragma unroll
    for (int fi = 0; fi < FIN; fi++) {
        float r = rows[nl * (FIN + 1) + fi];
        float4 wv = Ws4[fi * 8 + fo4];
        acc.x += r * wv.x;
        acc.y += r * wv.y;
        acc.z += r * wv.z;
        acc.w += r * wv.w;
    }
    float di = dinv[n];
    float4 bb = ((const float4*)bias)[fo4];
    float4 v;
    v.x = acc.x * di + bb.x;
    v.y = acc.y * di + bb.y;
    v.z = acc.z * di + bb.z;
    v.w = acc.w * di + bb.w;
    v.x = v.x > 0.f ? v.x : 0.f;
    v.y = v.y > 0.f ? v.y : 0.f;
    v.z = v.z > 0.f ? v.z : 0.f;
    v.w = v.w > 0.f ? v.w : 0.f;
    if (LAST) {
        ((float4*)outp)[(size_t)n * 8 + fo4] = v;
    } else {
        half4v hv;
        hv[0] = (_Float16)(v.x * di);
        hv[1] = (_Float16)(v.y * di);
        hv[2] = (_Float16)(v.z * di);
        hv[3] = (_Float16)(v.w * di);
        ((half4v*)outp)[(size_t)n * 8 + fo4] = hv;
    }
}

// ---- fc1 partials: part[b][g][j] = sum_{k in chunk b} h3[g][k]*w[k][j]; 4-deep ----
__global__ void fc1_kernel(const float* __restrict__ h3, const float* __restrict__ w,
                           float* __restrict__ part) {
    __shared__ float hs[NUM_GRAPHS * FC1_KCHUNK];  // 8 KB
    int t = threadIdx.x;
    int kbase = blockIdx.x * FC1_KCHUNK;
    for (int i = t; i < NUM_GRAPHS * FC1_KCHUNK; i += 256) {
        int g = i >> 7;  // FC1_KCHUNK == 128
        int kk = i & 127;
        hs[i] = h3[(size_t)g * FC1_IN + kbase + kk];
    }
    __syncthreads();
    int kl = t & 3;
    int c = t >> 2;
    float4 acc[NUM_GRAPHS];
#pragma unroll
    for (int g = 0; g < NUM_GRAPHS; g++) acc[g] = make_float4(0.f, 0.f, 0.f, 0.f);
    const float4* w4 = (const float4*)w;  // row k = 64 float4
    for (int i0 = 0; i0 < FC1_KCHUNK / 4; i0 += 4) {
        float4 wv[4];
#pragma unroll
        for (int u = 0; u < 4; u++)
            wv[u] = w4[(size_t)(kbase + kl + 4 * (i0 + u)) * (FC1_OUT / 4) + c];
#pragma unroll
        for (int u = 0; u < 4; u++) {
            int kk = kl + 4 * (i0 + u);
#pragma unroll
            for (int g = 0; g < NUM_GRAPHS; g++) {
                float hg = hs[g * FC1_KCHUNK + kk];
                acc[g].x += hg * wv[u].x;
                acc[g].y += hg * wv[u].y;
                acc[g].z += hg * wv[u].z;
                acc[g].w += hg * wv[u].w;
            }
        }
    }
#pragma unroll
    for (int g = 0; g < NUM_GRAPHS; g++) {
        acc[g].x += __shfl_xor(acc[g].x, 1);
        acc[g].y += __shfl_xor(acc[g].y, 1);
        acc[g].z += __shfl_xor(acc[g].z, 1);
        acc[g].w += __shfl_xor(acc[g].w, 1);
        acc[g].x += __shfl_xor(acc[g].x, 2);
        acc[g].y += __shfl_xor(acc[g].y, 2);
        acc[g].z += __shfl_xor(acc[g].z, 2);
        acc[g].w += __shfl_xor(acc[g].w, 2);
    }
    if (kl == 0) {
        float4* p4 = (float4*)part;
#pragma unroll
        for (int g = 0; g < NUM_GRAPHS; g++)
            p4[(size_t)blockIdx.x * (NUM_GRAPHS * FC1_OUT / 4) + g * (FC1_OUT / 4) + c] = acc[g];
    }
}

// ---- reduce partials -> partial8[bq][j']; no atomics, no memset needed ----
__global__ void reduce_kernel(const float* __restrict__ part, float* __restrict__ partial8) {
    int tid = blockIdx.x * 256 + threadIdx.x;  // 32768 threads
    int j = tid & 4095;
    int bq = tid >> 12;  // 0..7
    float s = 0.f;
#pragma unroll 8
    for (int u = 0; u < FC1_BLOCKS / 8; u++)
        s += part[(size_t)(bq * (FC1_BLOCKS / 8) + u) * (NUM_GRAPHS * FC1_OUT) + j];
    partial8[bq * (NUM_GRAPHS * FC1_OUT) + j] = s;
}

// ---- fc2: folds the 8 partials, bias+relu, then 256->64 matmul ----
__global__ void fc2_kernel(const float* __restrict__ partial8, const float* __restrict__ fc1_b,
                           const float* __restrict__ w2, const float* __restrict__ b2,
                           float* __restrict__ out) {
    int g = blockIdx.x;
    int j = threadIdx.x;  // 0..63
    __shared__ float vs[FC1_OUT];
    for (int k = j; k < FC1_OUT; k += 64) {
        float s = fc1_b[k];
#pragma unroll
        for (int bq = 0; bq < 8; bq++)
            s += partial8[bq * (NUM_GRAPHS * FC1_OUT) + g * FC1_OUT + k];
        vs[k] = s > 0.f ? s : 0.f;
    }
    __syncthreads();
    float acc = b2[j];
    for (int k = 0; k < FC1_OUT; k++) acc += vs[k] * w2[k * FC2_OUT + j];
    out[g * FC2_OUT + j] = acc;
}

extern "C" void kernel_launch(void* const* d_in, const int* in_sizes, int n_in,
                              void* d_out, int out_size, void* d_ws, size_t ws_size,
                              hipStream_t stream) {
    const float* x = (const float*)d_in[0];
    const int* ei = (const int*)d_in[1];
    const int* src = ei;
    const int* dst = ei + NUM_EDGES;
    const float* W1 = (const float*)d_in[2];
    const float* b1 = (const float*)d_in[3];
    const float* W2 = (const float*)d_in[4];
    const float* b2 = (const float*)d_in[5];
    const float* W3 = (const float*)d_in[6];
    const float* b3 = (const float*)d_in[7];
    const float* fc1_w = (const float*)d_in[8];
    const float* fc1_b = (const float*)d_in[9];
    const float* fc2_w = (const float*)d_in[10];
    const float* fc2_b = (const float*)d_in[11];
    float* out = (float*)d_out;

    // workspace layout (re-poisoned 0xAA each call)
    int* bucket_cursor = (int*)d_ws;                       // 1 KB
    int* binned = bucket_cursor + 256;                     // 5.24 MB
    unsigned short* csr = (unsigned short*)(binned + NB * BUCKET_CAP);  // 2.62 MB
    int* rowstart = (int*)(csr + NB * BUCKET_CAP);         // 256 KB
    int* rowend = rowstart + N_NODES;                      // 256 KB
    float* dinv = (float*)(rowend + N_NODES);              // 256 KB
    half8* p0 = (half8*)(dinv + N_NODES);                  // N*16 fp16 = 2 MB
    float* q0 = (float*)(p0 + (size_t)N_NODES * 2);        // N*16 f32 = 4 MB
    half8* p = (half8*)(q0 + (size_t)N_NODES * IN_FEAT);   // N*32 fp16 = 4 MB
    float* q = (float*)(p + (size_t)N_NODES * 4);          // N*32 f32 = 8 MB
    float* h3 = q + (size_t)N_NODES * HIDDEN;              // N*32 f32 = 8 MB
    float* part = h3 + (size_t)N_NODES * HIDDEN;           // 16 MB
    float* partial8 = part + (size_t)FC1_BLOCKS * NUM_GRAPHS * FC1_OUT;  // 128 KB

    initcur_kernel<<<1, 256, 0, stream>>>(bucket_cursor);
    binA_kernel<<<NUM_EDGES / EPB_A, 256, 0, stream>>>(src, dst, bucket_cursor, binned);
    sortB_kernel<<<NB, 512, 0, stream>>>(bucket_cursor, binned, csr, rowstart, rowend, dinv, x, p0);

    // layer 1: gather p0 (16 feats) -> q0, matmul W1 -> p (fp16, 32 feats)
    gather_kernel<2, 1><<<N_NODES * 2 / 256, 256, 0, stream>>>(rowstart, rowend, csr, p0, q0);
    matmul_kernel<IN_FEAT, false><<<N_NODES / 32, 256, 0, stream>>>(q0, W1, b1, dinv, p);

    // layer 2: gather p -> q, matmul W2 -> p (reuse q0 region? keep simple: q)
    gather_kernel<4, 2><<<N_NODES * 4 / 256, 256, 0, stream>>>(rowstart, rowend, csr, p, q);
    matmul_kernel<HIDDEN, false><<<N_NODES / 32, 256, 0, stream>>>(q, W2, b2, dinv, p);

    // layer 3: gather p -> q, matmul W3 -> h3 (fp32)
    gather_kernel<4, 2><<<N_NODES * 4 / 256, 256, 0, stream>>>(rowstart, rowend, csr, p, q);
    matmul_kernel<HIDDEN, true><<<N_NODES / 32, 256, 0, stream>>>(q, W3, b3, dinv, h3);

    fc1_kernel<<<FC1_BLOCKS, 256, 0, stream>>>(h3, fc1_w, part);
    reduce_kernel<<<128, 256, 0, stream>>>(part, partial8);
    fc2_kernel<<<NUM_GRAPHS, 64, 0, stream>>>(partial8, fc1_b, fc2_w, fc2_b, out);
}

// Round 9
// 311.678 us; speedup vs baseline: 1.1173x; 1.0495x over previous
//
#include <hip/hip_runtime.h>

#define N_NODES 65536
#define IN_FEAT 16
#define HIDDEN 32
#define NUM_EDGES 1048576
#define NUM_GRAPHS 16
#define NODES_PER_GRAPH 4096
#define FC1_IN (NODES_PER_GRAPH * HIDDEN) /* 131072 */
#define FC1_OUT 256
#define FC2_OUT 64
#define FC1_KCHUNK 128
#define FC1_BLOCKS (FC1_IN / FC1_KCHUNK) /* 1024 */
#define NB 256          /* buckets = dst>>8 */
#define BUCKET_CAP 5120 /* mean 4096, sd 64 -> 16 sigma headroom */
#define EPB_A 4096      /* edges per phase-A block */

typedef _Float16 half8 __attribute__((ext_vector_type(8)));  // 16 B

// ---- init bucket cursors to fixed-capacity bases ----
__global__ void initcur_kernel(int* __restrict__ bucket_cursor) {
    bucket_cursor[threadIdx.x] = threadIdx.x * BUCKET_CAP;
}

// ---- phase A: bin edges by dst>>8 with chunk-contiguous writes ----
__global__ void binA_kernel(const int* __restrict__ src, const int* __restrict__ dst,
                            int* __restrict__ bucket_cursor, int* __restrict__ binned) {
    __shared__ int hist[NB];
    __shared__ int base[NB];
    __shared__ int cur[NB];
    int t = threadIdx.x;
    hist[t] = 0;
    __syncthreads();
    int e0 = blockIdx.x * EPB_A;
    int s[16], d[16];
#pragma unroll
    for (int i = 0; i < 16; i++) {
        int e = e0 + t + 256 * i;
        s[i] = src[e];
        d[i] = dst[e];
    }
#pragma unroll
    for (int i = 0; i < 16; i++) atomicAdd(&hist[d[i] >> 8], 1);
    __syncthreads();
    base[t] = atomicAdd(&bucket_cursor[t], hist[t]);
    cur[t] = 0;
    __syncthreads();
#pragma unroll
    for (int i = 0; i < 16; i++) {
        int b = d[i] >> 8;
        int r = atomicAdd(&cur[b], 1);
        binned[base[b] + r] = s[i] | ((d[i] & 255) << 16);
    }
}

// ---- phase B: per-bucket LDS counting sort by dst low byte (512 threads) ----
// emits csr (ushort), rowstart/rowend, dinv, and p0 = x*dinv in fp16.
__global__ void sortB_kernel(const int* __restrict__ bucket_cursor, const int* __restrict__ binned,
                             unsigned short* __restrict__ csr, int* __restrict__ rowstart,
                             int* __restrict__ rowend, float* __restrict__ dinv,
                             const float* __restrict__ x, half8* __restrict__ p0) {
    __shared__ int hist[NB];
    __shared__ int scanbuf[NB];
    __shared__ int start[NB];
    __shared__ int cur[NB];
    int t = threadIdx.x;  // 0..511
    int b = blockIdx.x;
    int bbase = b * BUCKET_CAP;
    int cnt = bucket_cursor[b] - bbase;
    if (t < NB) hist[t] = 0;
    __syncthreads();
    for (int i = t; i < cnt; i += 512) atomicAdd(&hist[binned[bbase + i] >> 16], 1);
    __syncthreads();
    int v = 0;
    if (t < NB) {
        v = hist[t];
        scanbuf[t] = v;
    }
    __syncthreads();
    for (int off = 1; off < NB; off <<= 1) {
        int y = 0;
        if (t < NB && t >= off) y = scanbuf[t - off];
        __syncthreads();
        if (t < NB) scanbuf[t] += y;
        __syncthreads();
    }
    if (t < NB) {
        start[t] = scanbuf[t] - v;  // exclusive prefix within bucket
        cur[t] = 0;
    }
    __syncthreads();
    for (int i = t; i < cnt; i += 512) {
        int p = binned[bbase + i];
        int dl = p >> 16;
        int r = atomicAdd(&cur[dl], 1);
        csr[bbase + start[dl] + r] = (unsigned short)(p & 0xFFFF);
    }
    if (t < NB) {
        int n = b * NB + t;
        int excl = start[t];
        rowstart[n] = bbase + excl;
        rowend[n] = bbase + excl + v;
        dinv[n] = rsqrtf((float)v + 1.0f);
    }
    // p0 prescale: 512 threads = 256 nodes x 2 half8-chunks
    {
        int nl = t >> 1;
        int qq = t & 1;
        int n = b * NB + nl;
        float di = rsqrtf((float)hist[nl] + 1.0f);
        const float4* x4 = (const float4*)x;
        float4 a = x4[(size_t)n * 4 + 2 * qq];
        float4 c = x4[(size_t)n * 4 + 2 * qq + 1];
        half8 hh;
        hh[0] = (_Float16)(a.x * di); hh[1] = (_Float16)(a.y * di);
        hh[2] = (_Float16)(a.z * di); hh[3] = (_Float16)(a.w * di);
        hh[4] = (_Float16)(c.x * di); hh[5] = (_Float16)(c.y * di);
        hh[6] = (_Float16)(c.z * di); hh[7] = (_Float16)(c.w * di);
        p0[(size_t)n * 2 + qq] = hh;
    }
}

// ---- fused gather+matmul, quad-grain (no mid-kernel block barrier) ----
// q[n] = sum_{s in N(n)} p[s] + p[n]  (fp32 accum of fp16 rows, in registers)
// v = relu(dinv[n]*(q[n]@W) + b);  LAST: store fp32 h3, else p_next = v*dinv fp16.
// The F8 lanes of a node run identical-length loops -> butterfly shfl_xor
// (masks 1,2; stays in-quad) redistributes q; each lane computes its own
// contiguous 8/F8-float4 output group and stores its own half8 chunk(s).
template <int FIN, bool LAST>
__global__ void gmm_kernel(const int* __restrict__ rowstart, const int* __restrict__ rowend,
                           const unsigned short* __restrict__ csr, const half8* __restrict__ p,
                           const float* __restrict__ W, const float* __restrict__ bias,
                           const float* __restrict__ dinv, void* __restrict__ outp) {
    constexpr int F8 = FIN / 8;        // half8 chunks per input row: 2 or 4
    constexpr int LOG2F8 = (FIN == 16) ? 1 : 2;
    constexpr int NOUT4 = 8 / F8;      // float4 output groups per lane: 4 or 2
    __shared__ float4 Ws4[FIN * 8];    // W[FIN][32] as float4
    __shared__ float4 bs4[8];
    int t = threadIdx.x;
    for (int i = t; i < FIN * 8; i += 256) Ws4[i] = ((const float4*)W)[i];
    if (t < 8) bs4[t] = ((const float4*)bias)[t];
    __syncthreads();  // only barrier: before divergent work, no straggler cost

    int f8 = t & (F8 - 1);
    int n = (blockIdx.x * 256 + t) >> LOG2F8;

    // ---- gather stage ----
    half8 self = p[(size_t)n * F8 + f8];
    float acc[8];
#pragma unroll
    for (int e = 0; e < 8; e++) acc[e] = (float)self[e];
    int beg = rowstart[n];
    int end = rowend[n];
    int i = beg;
    for (; i + 8 <= end; i += 8) {
        int s[8];
#pragma unroll
        for (int u = 0; u < 8; u++) s[u] = csr[i + u];
        half8 a[8];
#pragma unroll
        for (int u = 0; u < 8; u++) a[u] = p[(size_t)s[u] * F8 + f8];
#pragma unroll
        for (int u = 0; u < 8; u++)
#pragma unroll
            for (int e = 0; e < 8; e++) acc[e] += (float)a[u][e];
    }
    if (i + 4 <= end) {
        int s[4];
#pragma unroll
        for (int u = 0; u < 4; u++) s[u] = csr[i + u];
        half8 a[4];
#pragma unroll
        for (int u = 0; u < 4; u++) a[u] = p[(size_t)s[u] * F8 + f8];
#pragma unroll
        for (int u = 0; u < 4; u++)
#pragma unroll
            for (int e = 0; e < 8; e++) acc[e] += (float)a[u][e];
        i += 4;
    }
    for (; i < end; i++) {
        half8 a = p[(size_t)csr[i] * F8 + f8];
#pragma unroll
        for (int e = 0; e < 8; e++) acc[e] += (float)a[e];
    }

    // ---- in-quad butterfly: lane gains all FIN q-features ----
    float a1[8], a2[8], a3[8];
#pragma unroll
    for (int e = 0; e < 8; e++) a1[e] = __shfl_xor(acc[e], 1);
    if (F8 == 4) {
#pragma unroll
        for (int e = 0; e < 8; e++) a2[e] = __shfl_xor(acc[e], 2);
#pragma unroll
        for (int e = 0; e < 8; e++) a3[e] = __shfl_xor(a1[e], 2);
    }

    // ---- per-lane matmul: outputs [f8*NOUT4*4 .. +NOUT4*4) ----
    int fo0 = f8 * NOUT4;
    float4 o4[NOUT4];
#pragma unroll
    for (int j = 0; j < NOUT4; j++) o4[j] = make_float4(0.f, 0.f, 0.f, 0.f);

#define MM_CHUNK(AR, C)                                               \
    {                                                                 \
        int c_ = (C);                                                 \
        _Pragma("unroll") for (int e = 0; e < 8; e++) {               \
            int fi = c_ * 8 + e;                                      \
            float r = (AR)[e];                                        \
            _Pragma("unroll") for (int j = 0; j < NOUT4; j++) {       \
                float4 wv = Ws4[fi * 8 + fo0 + j];                    \
                o4[j].x += r * wv.x;                                  \
                o4[j].y += r * wv.y;                                  \
                o4[j].z += r * wv.z;                                  \
                o4[j].w += r * wv.w;                                  \
            }                                                         \
        }                                                             \
    }

    MM_CHUNK(acc, f8)
    MM_CHUNK(a1, f8 ^ 1)
    if (F8 == 4) {
        MM_CHUNK(a2, f8 ^ 2)
        MM_CHUNK(a3, f8 ^ 3)
    }
#undef MM_CHUNK

    // ---- epilogue ----
    float di = dinv[n];
    float4 v4[NOUT4];
#pragma unroll
    for (int j = 0; j < NOUT4; j++) {
        float4 bb = bs4[fo0 + j];
        float4 v;
        v.x = o4[j].x * di + bb.x;
        v.y = o4[j].y * di + bb.y;
        v.z = o4[j].z * di + bb.z;
        v.w = o4[j].w * di + bb.w;
        v.x = v.x > 0.f ? v.x : 0.f;
        v.y = v.y > 0.f ? v.y : 0.f;
        v.z = v.z > 0.f ? v.z : 0.f;
        v.w = v.w > 0.f ? v.w : 0.f;
        v4[j] = v;
    }
    if (LAST) {
        float4* o = (float4*)outp;
#pragma unroll
        for (int j = 0; j < NOUT4; j++) o[(size_t)n * 8 + fo0 + j] = v4[j];
    } else {
        half8* o = (half8*)outp;
#pragma unroll
        for (int pr = 0; pr < NOUT4 / 2; pr++) {
            float4 lo = v4[2 * pr], hi = v4[2 * pr + 1];
            half8 hh;
            hh[0] = (_Float16)(lo.x * di); hh[1] = (_Float16)(lo.y * di);
            hh[2] = (_Float16)(lo.z * di); hh[3] = (_Float16)(lo.w * di);
            hh[4] = (_Float16)(hi.x * di); hh[5] = (_Float16)(hi.y * di);
            hh[6] = (_Float16)(hi.z * di); hh[7] = (_Float16)(hi.w * di);
            o[(size_t)n * 4 + fo0 / 2 + pr] = hh;
        }
    }
}

// ---- fc1 partials: part[b][g][j] = sum_{k in chunk b} h3[g][k]*w[k][j]; 4-deep ----
__global__ void fc1_kernel(const float* __restrict__ h3, const float* __restrict__ w,
                           float* __restrict__ part) {
    __shared__ float hs[NUM_GRAPHS * FC1_KCHUNK];  // 8 KB
    int t = threadIdx.x;
    int kbase = blockIdx.x * FC1_KCHUNK;
    for (int i = t; i < NUM_GRAPHS * FC1_KCHUNK; i += 256) {
        int g = i >> 7;  // FC1_KCHUNK == 128
        int kk = i & 127;
        hs[i] = h3[(size_t)g * FC1_IN + kbase + kk];
    }
    __syncthreads();
    int kl = t & 3;
    int c = t >> 2;
    float4 acc[NUM_GRAPHS];
#pragma unroll
    for (int g = 0; g < NUM_GRAPHS; g++) acc[g] = make_float4(0.f, 0.f, 0.f, 0.f);
    const float4* w4 = (const float4*)w;  // row k = 64 float4
    for (int i0 = 0; i0 < FC1_KCHUNK / 4; i0 += 4) {
        float4 wv[4];
#pragma unroll
        for (int u = 0; u < 4; u++)
            wv[u] = w4[(size_t)(kbase + kl + 4 * (i0 + u)) * (FC1_OUT / 4) + c];
#pragma unroll
        for (int u = 0; u < 4; u++) {
            int kk = kl + 4 * (i0 + u);
#pragma unroll
            for (int g = 0; g < NUM_GRAPHS; g++) {
                float hg = hs[g * FC1_KCHUNK + kk];
                acc[g].x += hg * wv[u].x;
                acc[g].y += hg * wv[u].y;
                acc[g].z += hg * wv[u].z;
                acc[g].w += hg * wv[u].w;
            }
        }
    }
#pragma unroll
    for (int g = 0; g < NUM_GRAPHS; g++) {
        acc[g].x += __shfl_xor(acc[g].x, 1);
        acc[g].y += __shfl_xor(acc[g].y, 1);
        acc[g].z += __shfl_xor(acc[g].z, 1);
        acc[g].w += __shfl_xor(acc[g].w, 1);
        acc[g].x += __shfl_xor(acc[g].x, 2);
        acc[g].y += __shfl_xor(acc[g].y, 2);
        acc[g].z += __shfl_xor(acc[g].z, 2);
        acc[g].w += __shfl_xor(acc[g].w, 2);
    }
    if (kl == 0) {
        float4* p4 = (float4*)part;
#pragma unroll
        for (int g = 0; g < NUM_GRAPHS; g++)
            p4[(size_t)blockIdx.x * (NUM_GRAPHS * FC1_OUT / 4) + g * (FC1_OUT / 4) + c] = acc[g];
    }
}

// ---- reduce partials -> partial8[bq][j']; no atomics, no memset needed ----
__global__ void reduce_kernel(const float* __restrict__ part, float* __restrict__ partial8) {
    int tid = blockIdx.x * 256 + threadIdx.x;  // 32768 threads
    int j = tid & 4095;
    int bq = tid >> 12;  // 0..7
    float s = 0.f;
#pragma unroll 8
    for (int u = 0; u < FC1_BLOCKS / 8; u++)
        s += part[(size_t)(bq * (FC1_BLOCKS / 8) + u) * (NUM_GRAPHS * FC1_OUT) + j];
    partial8[bq * (NUM_GRAPHS * FC1_OUT) + j] = s;
}

// ---- fc2: folds the 8 partials, bias+relu, then 256->64 matmul ----
__global__ void fc2_kernel(const float* __restrict__ partial8, const float* __restrict__ fc1_b,
                           const float* __restrict__ w2, const float* __restrict__ b2,
                           float* __restrict__ out) {
    int g = blockIdx.x;
    int j = threadIdx.x;  // 0..63
    __shared__ float vs[FC1_OUT];
    for (int k = j; k < FC1_OUT; k += 64) {
        float s = fc1_b[k];
#pragma unroll
        for (int bq = 0; bq < 8; bq++)
            s += partial8[bq * (NUM_GRAPHS * FC1_OUT) + g * FC1_OUT + k];
        vs[k] = s > 0.f ? s : 0.f;
    }
    __syncthreads();
    float acc = b2[j];
    for (int k = 0; k < FC1_OUT; k++) acc += vs[k] * w2[k * FC2_OUT + j];
    out[g * FC2_OUT + j] = acc;
}

extern "C" void kernel_launch(void* const* d_in, const int* in_sizes, int n_in,
                              void* d_out, int out_size, void* d_ws, size_t ws_size,
                              hipStream_t stream) {
    const float* x = (const float*)d_in[0];
    const int* ei = (const int*)d_in[1];
    const int* src = ei;
    const int* dst = ei + NUM_EDGES;
    const float* W1 = (const float*)d_in[2];
    const float* b1 = (const float*)d_in[3];
    const float* W2 = (const float*)d_in[4];
    const float* b2 = (const float*)d_in[5];
    const float* W3 = (const float*)d_in[6];
    const float* b3 = (const float*)d_in[7];
    const float* fc1_w = (const float*)d_in[8];
    const float* fc1_b = (const float*)d_in[9];
    const float* fc2_w = (const float*)d_in[10];
    const float* fc2_b = (const float*)d_in[11];
    float* out = (float*)d_out;

    // workspace layout (re-poisoned 0xAA each call)
    int* bucket_cursor = (int*)d_ws;                       // 1 KB
    int* binned = bucket_cursor + 256;                     // 5.24 MB
    unsigned short* csr = (unsigned short*)(binned + NB * BUCKET_CAP);  // 2.62 MB
    int* rowstart = (int*)(csr + NB * BUCKET_CAP);         // 256 KB
    int* rowend = rowstart + N_NODES;                      // 256 KB
    float* dinv = (float*)(rowend + N_NODES);              // 256 KB
    half8* p0 = (half8*)(dinv + N_NODES);                  // N*16 fp16 = 2 MB
    half8* pA = (half8*)(p0 + (size_t)N_NODES * 2);        // N*32 fp16 = 4 MB
    half8* pB = (half8*)(pA + (size_t)N_NODES * 4);        // N*32 fp16 = 4 MB
    float* h3 = (float*)(pB + (size_t)N_NODES * 4);        // N*32 f32 = 8 MB
    float* part = h3 + (size_t)N_NODES * HIDDEN;           // 16 MB
    float* partial8 = part + (size_t)FC1_BLOCKS * NUM_GRAPHS * FC1_OUT;  // 128 KB

    initcur_kernel<<<1, 256, 0, stream>>>(bucket_cursor);
    binA_kernel<<<NUM_EDGES / EPB_A, 256, 0, stream>>>(src, dst, bucket_cursor, binned);
    sortB_kernel<<<NB, 512, 0, stream>>>(bucket_cursor, binned, csr, rowstart, rowend, dinv, x, p0);

    // layer 1: fused gather(16-feat p0) + matmul W1 -> pA (fp16)
    gmm_kernel<IN_FEAT, false><<<N_NODES * 2 / 256, 256, 0, stream>>>(
        rowstart, rowend, csr, p0, W1, b1, dinv, pA);
    // layer 2: fused gather(32-feat pA) + matmul W2 -> pB (fp16)
    gmm_kernel<HIDDEN, false><<<N_NODES * 4 / 256, 256, 0, stream>>>(
        rowstart, rowend, csr, pA, W2, b2, dinv, pB);
    // layer 3: fused gather(32-feat pB) + matmul W3 -> h3 (fp32)
    gmm_kernel<HIDDEN, true><<<N_NODES * 4 / 256, 256, 0, stream>>>(
        rowstart, rowend, csr, pB, W3, b3, dinv, h3);

    fc1_kernel<<<FC1_BLOCKS, 256, 0, stream>>>(h3, fc1_w, part);
    reduce_kernel<<<128, 256, 0, stream>>>(part, partial8);
    fc2_kernel<<<NUM_GRAPHS, 64, 0, stream>>>(partial8, fc1_b, fc2_w, fc2_b, out);
}